// Round 2
// baseline (2214.291 us; speedup 1.0000x reference)
//
#include <hip/hip_runtime.h>

// GCN layer, E=1.6M, N=50000, F=48.
//   node_h = segment_mean(edge_feats, dst)
//   h2     = segment_sum(node_h[src], dst)
//   out[e] = 0.5*(h2[src]+h2[dst]) @ W^T + b
// Key algebra: linear commutes with gather/add ->
//   h2W = 0.5*(h2 @ W^T) + 0.5*b  (node level, 50K rows)
//   out[e] = h2W[src[e]] + h2W[dst[e]]   (pure gather+add, BW-bound)

constexpr int NN = 50000;
constexpr int F  = 48;
constexpr int F4 = F / 4;   // 12 float4 per row

// thread per (edge, float4): nsum[dst[e]] += ef[e]; lane q==0 counts degree
__global__ void k_scatter_ef(const float4* __restrict__ ef4, const int* __restrict__ dst,
                             float* __restrict__ nsum, float* __restrict__ deg, int total) {
    int idx = blockIdx.x * blockDim.x + threadIdx.x;
    if (idx >= total) return;
    int e = idx / F4;
    int q = idx - e * F4;
    float4 v = ef4[idx];
    int d = dst[e];
    float* p = nsum + d * F + q * 4;
    atomicAdd(p + 0, v.x);
    atomicAdd(p + 1, v.y);
    atomicAdd(p + 2, v.z);
    atomicAdd(p + 3, v.w);
    if (q == 0) atomicAdd(&deg[d], 1.0f);
}

// node_h = nsum / max(deg,1), in place
__global__ void k_node_div(float* __restrict__ nsum, const float* __restrict__ deg, int total) {
    int i = blockIdx.x * blockDim.x + threadIdx.x;
    if (i >= total) return;
    float d = deg[i / F];
    nsum[i] = nsum[i] / fmaxf(d, 1.0f);
}

// thread per (edge, float4): h2[dst[e]] += node_h[src[e]]  (node_h L2-resident)
__global__ void k_scatter_h2(const float4* __restrict__ nh4, const int* __restrict__ src,
                             const int* __restrict__ dst, float* __restrict__ h2, int total) {
    int idx = blockIdx.x * blockDim.x + threadIdx.x;
    if (idx >= total) return;
    int e = idx / F4;
    int q = idx - e * F4;
    float4 v = nh4[src[e] * F4 + q];
    int d = dst[e];
    float* p = h2 + d * F + q * 4;
    atomicAdd(p + 0, v.x);
    atomicAdd(p + 1, v.y);
    atomicAdd(p + 2, v.z);
    atomicAdd(p + 3, v.w);
}

// one thread per node: h2W[n] = 0.5*(h2[n] @ W^T) + 0.5*b   (tiny: 50K x 48x48)
__global__ __launch_bounds__(256) void k_node_linear(
    const float* __restrict__ h2, const float* __restrict__ W,
    const float* __restrict__ b, float* __restrict__ h2W, int n)
{
    int v = blockIdx.x * blockDim.x + threadIdx.x;
    if (v >= n) return;
    float eh[F];
    const float4* hr = (const float4*)(h2 + (long long)v * F);
#pragma unroll
    for (int i = 0; i < F4; i++) {
        float4 a = hr[i];
        eh[4 * i + 0] = a.x; eh[4 * i + 1] = a.y;
        eh[4 * i + 2] = a.z; eh[4 * i + 3] = a.w;
    }
    float4* o4 = (float4*)(h2W + (long long)v * F);
    for (int o = 0; o < F; o += 4) {
        float4 acc = make_float4(0.f, 0.f, 0.f, 0.f);
#pragma unroll
        for (int i = 0; i < F; i++) {
            acc.x += eh[i] * W[(o + 0) * F + i];
            acc.y += eh[i] * W[(o + 1) * F + i];
            acc.z += eh[i] * W[(o + 2) * F + i];
            acc.w += eh[i] * W[(o + 3) * F + i];
        }
        acc.x = 0.5f * acc.x + 0.5f * b[o + 0];
        acc.y = 0.5f * acc.y + 0.5f * b[o + 1];
        acc.z = 0.5f * acc.z + 0.5f * b[o + 2];
        acc.w = 0.5f * acc.w + 0.5f * b[o + 3];
        o4[o / 4] = acc;
    }
}

// thread per (edge, float4): out = h2W[src] + h2W[dst]; coalesced 16B stores
__global__ void k_edge_out(const int* __restrict__ src, const int* __restrict__ dst,
                           const float4* __restrict__ h2W4, float4* __restrict__ out4, int total) {
    int idx = blockIdx.x * blockDim.x + threadIdx.x;
    if (idx >= total) return;
    int e = idx / F4;
    int q = idx - e * F4;
    float4 x = h2W4[src[e] * F4 + q];
    float4 y = h2W4[dst[e] * F4 + q];
    float4 r;
    r.x = x.x + y.x; r.y = x.y + y.y; r.z = x.z + y.z; r.w = x.w + y.w;
    out4[idx] = r;
}

extern "C" void kernel_launch(void* const* d_in, const int* in_sizes, int n_in,
                              void* d_out, int out_size, void* d_ws, size_t ws_size,
                              hipStream_t stream) {
    const float* ef  = (const float*)d_in[0];
    const int*   src = (const int*)d_in[1];
    const int*   dst = (const int*)d_in[2];
    const float* W   = (const float*)d_in[3];
    const float* b   = (const float*)d_in[4];
    float* out = (float*)d_out;
    const int E = in_sizes[1];

    // ws layout: nsum/node_h [NN*F] | h2 [NN*F] | h2W [NN*F] | deg [NN]
    float* nsum = (float*)d_ws;
    float* h2   = nsum + NN * F;
    float* h2W  = h2 + NN * F;
    float* deg  = h2W + NN * F;
    // zero nsum, h2, deg (h2W is fully overwritten)
    hipMemsetAsync(nsum, 0, (size_t)(2 * NN * F) * sizeof(float), stream);
    hipMemsetAsync(deg, 0, (size_t)NN * sizeof(float), stream);

    const int totE4 = E * F4;        // 19.2M
    const int totNF = NN * F;        // 2.4M

    k_scatter_ef<<<(totE4 + 255) / 256, 256, 0, stream>>>(
        (const float4*)ef, dst, nsum, deg, totE4);
    k_node_div<<<(totNF + 255) / 256, 256, 0, stream>>>(nsum, deg, totNF);
    k_scatter_h2<<<(totE4 + 255) / 256, 256, 0, stream>>>(
        (const float4*)nsum, src, dst, h2, totE4);
    k_node_linear<<<(NN + 255) / 256, 256, 0, stream>>>(h2, W, b, h2W, NN);
    k_edge_out<<<(totE4 + 255) / 256, 256, 0, stream>>>(
        src, dst, (const float4*)h2W, (float4*)out, totE4);
}

// Round 3
// 637.355 us; speedup vs baseline: 3.4742x; 3.4742x over previous
//
#include <hip/hip_runtime.h>

// GCN layer, E=1.6M, N=50000, F=48.
//   node_h = segment_mean(edge_feats, dst)
//   h2     = segment_sum(node_h[src], dst)
//   out[e] = 0.5*(h2[src]+h2[dst]) @ W^T + b
// Algebra: h2W = 0.5*(h2 @ W^T) + 0.5*b (node level); out[e]=h2W[src]+h2W[dst].
// Round-2 lesson: fp atomics cost ~1 line-transaction per ~4 atomics to memory
// (WRITE_SIZE 1.28GB for a 9.6MB dest). So: build CSR by dst (3.2M int atomics
// total) and turn both segment-sums into gather-sums.

constexpr int NN = 50000;
constexpr int F  = 48;
constexpr int F4 = F / 4;

// ---- CSR build ----------------------------------------------------------
__global__ void k_count(const int* __restrict__ dst, int* __restrict__ cnt, int E) {
    int e = blockIdx.x * blockDim.x + threadIdx.x;
    if (e < E) atomicAdd(&cnt[dst[e]], 1);
}

// single-block exclusive scan of cnt[0..n) -> rowptr, cursor; rowptr[n]=total
__global__ void k_scan(const int* __restrict__ cnt, int* __restrict__ rowptr,
                       int* __restrict__ cursor, int n) {
    __shared__ int s[1024];
    int t = threadIdx.x;
    int chunk = (n + 1023) / 1024;
    int lo = t * chunk, hi = min(lo + chunk, n);
    int sum = 0;
    for (int i = lo; i < hi; i++) sum += cnt[i];
    s[t] = sum;
    __syncthreads();
    for (int d = 1; d < 1024; d <<= 1) {
        int v = (t >= d) ? s[t - d] : 0;
        __syncthreads();
        s[t] += v;
        __syncthreads();
    }
    int run = (t == 0) ? 0 : s[t - 1];
    for (int i = lo; i < hi; i++) {
        rowptr[i] = run;
        cursor[i] = run;
        run += cnt[i];
    }
    if (t == 0) rowptr[n] = s[1023];
}

// place edge ids (and their src) into dst-sorted order
__global__ void k_fill(const int* __restrict__ src, const int* __restrict__ dst,
                       int* __restrict__ cursor, int* __restrict__ csr_e,
                       int* __restrict__ csr_src, int E) {
    int e = blockIdx.x * blockDim.x + threadIdx.x;
    if (e >= E) return;
    int pos = atomicAdd(&cursor[dst[e]], 1);
    csr_e[pos]   = e;
    csr_src[pos] = src[e];
}

// ---- gather-sums --------------------------------------------------------
// thread per (node, f): node_h = mean of in-edge features. 48 lanes of a node
// read one contiguous 192B edge row per iteration (coalesced).
__global__ __launch_bounds__(256) void k_node_h(
    const float* __restrict__ ef, const int* __restrict__ csr_e,
    const int* __restrict__ rowptr, float* __restrict__ node_h, int total)
{
    int idx = blockIdx.x * blockDim.x + threadIdx.x;
    if (idx >= total) return;
    int n = idx / F;
    int f = idx - n * F;
    int lo = rowptr[n], hi = rowptr[n + 1];
    float acc = 0.f;
    int j = lo;
    for (; j + 4 <= hi; j += 4) {           // 4 independent loads in flight
        int e0 = csr_e[j], e1 = csr_e[j + 1], e2 = csr_e[j + 2], e3 = csr_e[j + 3];
        float a0 = ef[e0 * F + f], a1 = ef[e1 * F + f];
        float a2 = ef[e2 * F + f], a3 = ef[e3 * F + f];
        acc += a0; acc += a1; acc += a2; acc += a3;
    }
    for (; j < hi; j++) acc += ef[csr_e[j] * F + f];
    node_h[idx] = acc / fmaxf((float)(hi - lo), 1.0f);
}

// thread per (node, f): h2 = sum of node_h[src] over in-edges (all L2-resident)
__global__ __launch_bounds__(256) void k_h2(
    const float* __restrict__ node_h, const int* __restrict__ csr_src,
    const int* __restrict__ rowptr, float* __restrict__ h2, int total)
{
    int idx = blockIdx.x * blockDim.x + threadIdx.x;
    if (idx >= total) return;
    int n = idx / F;
    int f = idx - n * F;
    int lo = rowptr[n], hi = rowptr[n + 1];
    float acc = 0.f;
    int j = lo;
    for (; j + 4 <= hi; j += 4) {
        int s0 = csr_src[j], s1 = csr_src[j + 1], s2 = csr_src[j + 2], s3 = csr_src[j + 3];
        float a0 = node_h[s0 * F + f], a1 = node_h[s1 * F + f];
        float a2 = node_h[s2 * F + f], a3 = node_h[s3 * F + f];
        acc += a0; acc += a1; acc += a2; acc += a3;
    }
    for (; j < hi; j++) acc += node_h[csr_src[j] * F + f];
    h2[idx] = acc;
}

// ---- node-level linear, then per-edge gather+add ------------------------
__global__ __launch_bounds__(256) void k_node_linear(
    const float* __restrict__ h2, const float* __restrict__ W,
    const float* __restrict__ b, float* __restrict__ h2W, int n)
{
    int v = blockIdx.x * blockDim.x + threadIdx.x;
    if (v >= n) return;
    float eh[F];
    const float4* hr = (const float4*)(h2 + (long long)v * F);
#pragma unroll
    for (int i = 0; i < F4; i++) {
        float4 a = hr[i];
        eh[4 * i + 0] = a.x; eh[4 * i + 1] = a.y;
        eh[4 * i + 2] = a.z; eh[4 * i + 3] = a.w;
    }
    float4* o4 = (float4*)(h2W + (long long)v * F);
    for (int o = 0; o < F; o += 4) {
        float4 acc = make_float4(0.f, 0.f, 0.f, 0.f);
#pragma unroll
        for (int i = 0; i < F; i++) {
            acc.x += eh[i] * W[(o + 0) * F + i];
            acc.y += eh[i] * W[(o + 1) * F + i];
            acc.z += eh[i] * W[(o + 2) * F + i];
            acc.w += eh[i] * W[(o + 3) * F + i];
        }
        acc.x = 0.5f * acc.x + 0.5f * b[o + 0];
        acc.y = 0.5f * acc.y + 0.5f * b[o + 1];
        acc.z = 0.5f * acc.z + 0.5f * b[o + 2];
        acc.w = 0.5f * acc.w + 0.5f * b[o + 3];
        o4[o / 4] = acc;
    }
}

// thread per (edge, float4): out = h2W[src] + h2W[dst]; coalesced 16B stores
__global__ void k_edge_out(const int* __restrict__ src, const int* __restrict__ dst,
                           const float4* __restrict__ h2W4, float4* __restrict__ out4, int total) {
    int idx = blockIdx.x * blockDim.x + threadIdx.x;
    if (idx >= total) return;
    int e = idx / F4;
    int q = idx - e * F4;
    float4 x = h2W4[src[e] * F4 + q];
    float4 y = h2W4[dst[e] * F4 + q];
    float4 r;
    r.x = x.x + y.x; r.y = x.y + y.y; r.z = x.z + y.z; r.w = x.w + y.w;
    out4[idx] = r;
}

extern "C" void kernel_launch(void* const* d_in, const int* in_sizes, int n_in,
                              void* d_out, int out_size, void* d_ws, size_t ws_size,
                              hipStream_t stream) {
    const float* ef  = (const float*)d_in[0];
    const int*   src = (const int*)d_in[1];
    const int*   dst = (const int*)d_in[2];
    const float* W   = (const float*)d_in[3];
    const float* b   = (const float*)d_in[4];
    float* out = (float*)d_out;
    const int E = in_sizes[1];

    // ws layout (floats first for 16B alignment of float4 accesses)
    float* node_h = (float*)d_ws;              // NN*F
    float* h2     = node_h + NN * F;           // NN*F
    float* h2W    = h2 + NN * F;               // NN*F
    int* csr_e    = (int*)(h2W + NN * F);      // E
    int* csr_src  = csr_e + E;                 // E
    int* rowptr   = csr_src + E;               // NN+1
    int* cnt      = rowptr + NN + 1;           // NN
    int* cursor   = cnt + NN;                  // NN

    hipMemsetAsync(cnt, 0, (size_t)NN * sizeof(int), stream);

    const int totNF = NN * F;                  // 2.4M
    const int totE4 = E * F4;                  // 19.2M

    k_count<<<(E + 255) / 256, 256, 0, stream>>>(dst, cnt, E);
    k_scan<<<1, 1024, 0, stream>>>(cnt, rowptr, cursor, NN);
    k_fill<<<(E + 255) / 256, 256, 0, stream>>>(src, dst, cursor, csr_e, csr_src, E);
    k_node_h<<<(totNF + 255) / 256, 256, 0, stream>>>(ef, csr_e, rowptr, node_h, totNF);
    k_h2<<<(totNF + 255) / 256, 256, 0, stream>>>(node_h, csr_src, rowptr, h2, totNF);
    k_node_linear<<<(NN + 255) / 256, 256, 0, stream>>>(h2, W, b, h2W, NN);
    k_edge_out<<<(totE4 + 255) / 256, 256, 0, stream>>>(
        src, dst, (const float4*)h2W, (float4*)out, totE4);
}

// Round 5
// 589.128 us; speedup vs baseline: 3.7586x; 1.0819x over previous
//
#include <hip/hip_runtime.h>

// GCN layer, E=1.6M, N=50000, F=48.
//   node_h = segment_mean(edge_feats, dst)
//   h2     = segment_sum(node_h[src], dst)
//   out[e] = 0.5*(h2[src]+h2[dst]) @ W^T + b
// Algebra: h2W = 0.5*(h2 @ W^T) + 0.5*b (node level); out[e]=h2W[src]+h2W[dst].
// R2 lesson: fp atomics -> ~1 memory transaction per ~4 atomics; use CSR + gather.
// R3 lesson: in-graph hipMemsetAsync(200KB) dispatches a 176us fill (!) -> own kernel.
// R4 lesson: __builtin_nontemporal_* needs native vector types, not HIP float4.

constexpr int NN = 50000;
constexpr int F  = 48;
constexpr int F4 = F / 4;

typedef float f32x4 __attribute__((ext_vector_type(4)));

// ---- tiny zero ----------------------------------------------------------
__global__ void k_zero(int* __restrict__ p, int n) {
    int i = blockIdx.x * blockDim.x + threadIdx.x;
    if (i < n) p[i] = 0;
}

// ---- CSR build ----------------------------------------------------------
__global__ void k_count(const int* __restrict__ dst, int* __restrict__ cnt, int E) {
    int e = blockIdx.x * blockDim.x + threadIdx.x;
    if (e < E) atomicAdd(&cnt[dst[e]], 1);
}

// single-block exclusive scan of cnt[0..n) -> rowptr, cursor; rowptr[n]=total
__global__ void k_scan(const int* __restrict__ cnt, int* __restrict__ rowptr,
                       int* __restrict__ cursor, int n) {
    __shared__ int s[1024];
    int t = threadIdx.x;
    int chunk = (n + 1023) / 1024;
    int lo = t * chunk, hi = min(lo + chunk, n);
    int sum = 0;
    for (int i = lo; i < hi; i++) sum += cnt[i];
    s[t] = sum;
    __syncthreads();
    for (int d = 1; d < 1024; d <<= 1) {
        int v = (t >= d) ? s[t - d] : 0;
        __syncthreads();
        s[t] += v;
        __syncthreads();
    }
    int run = (t == 0) ? 0 : s[t - 1];
    for (int i = lo; i < hi; i++) {
        rowptr[i] = run;
        cursor[i] = run;
        run += cnt[i];
    }
    if (t == 0) rowptr[n] = s[1023];
}

// place edge ids (and their src) into dst-sorted order
__global__ void k_fill(const int* __restrict__ src, const int* __restrict__ dst,
                       int* __restrict__ cursor, int* __restrict__ csr_e,
                       int* __restrict__ csr_src, int E) {
    int e = blockIdx.x * blockDim.x + threadIdx.x;
    if (e >= E) return;
    int pos = atomicAdd(&cursor[dst[e]], 1);
    csr_e[pos]   = e;
    csr_src[pos] = src[e];
}

// ---- gather-sums (thread per (node, float4)) ----------------------------
__global__ __launch_bounds__(256) void k_node_h(
    const f32x4* __restrict__ ef4, const int* __restrict__ csr_e,
    const int* __restrict__ rowptr, f32x4* __restrict__ node_h4, int total)
{
    int idx = blockIdx.x * blockDim.x + threadIdx.x;
    if (idx >= total) return;
    int n = idx / F4;
    int q = idx - n * F4;
    int lo = rowptr[n], hi = rowptr[n + 1];
    f32x4 acc = (f32x4)(0.f);
    int j = lo;
    for (; j + 4 <= hi; j += 4) {           // 4 x 16B loads in flight
        int e0 = csr_e[j], e1 = csr_e[j + 1], e2 = csr_e[j + 2], e3 = csr_e[j + 3];
        f32x4 a0 = __builtin_nontemporal_load(&ef4[e0 * F4 + q]);
        f32x4 a1 = __builtin_nontemporal_load(&ef4[e1 * F4 + q]);
        f32x4 a2 = __builtin_nontemporal_load(&ef4[e2 * F4 + q]);
        f32x4 a3 = __builtin_nontemporal_load(&ef4[e3 * F4 + q]);
        acc += a0 + a1 + a2 + a3;
    }
    for (; j < hi; j++)
        acc += __builtin_nontemporal_load(&ef4[csr_e[j] * F4 + q]);
    float inv = 1.0f / fmaxf((float)(hi - lo), 1.0f);
    node_h4[idx] = acc * inv;
}

__global__ __launch_bounds__(256) void k_h2(
    const f32x4* __restrict__ nh4, const int* __restrict__ csr_src,
    const int* __restrict__ rowptr, f32x4* __restrict__ h2_4, int total)
{
    int idx = blockIdx.x * blockDim.x + threadIdx.x;
    if (idx >= total) return;
    int n = idx / F4;
    int q = idx - n * F4;
    int lo = rowptr[n], hi = rowptr[n + 1];
    f32x4 acc = (f32x4)(0.f);
    int j = lo;
    for (; j + 4 <= hi; j += 4) {
        int s0 = csr_src[j], s1 = csr_src[j + 1], s2 = csr_src[j + 2], s3 = csr_src[j + 3];
        f32x4 a0 = nh4[s0 * F4 + q];
        f32x4 a1 = nh4[s1 * F4 + q];
        f32x4 a2 = nh4[s2 * F4 + q];
        f32x4 a3 = nh4[s3 * F4 + q];
        acc += a0 + a1 + a2 + a3;
    }
    for (; j < hi; j++)
        acc += nh4[csr_src[j] * F4 + q];
    h2_4[idx] = acc;
}

// ---- node-level linear --------------------------------------------------
__global__ __launch_bounds__(256) void k_node_linear(
    const float* __restrict__ h2, const float* __restrict__ W,
    const float* __restrict__ b, float* __restrict__ h2W, int n)
{
    int v = blockIdx.x * blockDim.x + threadIdx.x;
    if (v >= n) return;
    float eh[F];
    const float4* hr = (const float4*)(h2 + (long long)v * F);
#pragma unroll
    for (int i = 0; i < F4; i++) {
        float4 a = hr[i];
        eh[4 * i + 0] = a.x; eh[4 * i + 1] = a.y;
        eh[4 * i + 2] = a.z; eh[4 * i + 3] = a.w;
    }
    float4* o4 = (float4*)(h2W + (long long)v * F);
    for (int o = 0; o < F; o += 4) {
        float4 acc = make_float4(0.f, 0.f, 0.f, 0.f);
#pragma unroll
        for (int i = 0; i < F; i++) {
            acc.x += eh[i] * W[(o + 0) * F + i];
            acc.y += eh[i] * W[(o + 1) * F + i];
            acc.z += eh[i] * W[(o + 2) * F + i];
            acc.w += eh[i] * W[(o + 3) * F + i];
        }
        acc.x = 0.5f * acc.x + 0.5f * b[o + 0];
        acc.y = 0.5f * acc.y + 0.5f * b[o + 1];
        acc.z = 0.5f * acc.z + 0.5f * b[o + 2];
        acc.w = 0.5f * acc.w + 0.5f * b[o + 3];
        o4[o / 4] = acc;
    }
}

// thread per (edge, float4): out = h2W[src] + h2W[dst]; nt stores (write-once)
__global__ void k_edge_out(const int* __restrict__ src, const int* __restrict__ dst,
                           const f32x4* __restrict__ h2W4, f32x4* __restrict__ out4, int total) {
    int idx = blockIdx.x * blockDim.x + threadIdx.x;
    if (idx >= total) return;
    int e = idx / F4;
    int q = idx - e * F4;
    f32x4 x = h2W4[src[e] * F4 + q];
    f32x4 y = h2W4[dst[e] * F4 + q];
    f32x4 r = x + y;
    __builtin_nontemporal_store(r, &out4[idx]);
}

extern "C" void kernel_launch(void* const* d_in, const int* in_sizes, int n_in,
                              void* d_out, int out_size, void* d_ws, size_t ws_size,
                              hipStream_t stream) {
    const float* ef  = (const float*)d_in[0];
    const int*   src = (const int*)d_in[1];
    const int*   dst = (const int*)d_in[2];
    const float* W   = (const float*)d_in[3];
    const float* b   = (const float*)d_in[4];
    float* out = (float*)d_out;
    const int E = in_sizes[1];

    // ws layout (floats first for 16B alignment of float4 accesses)
    float* node_h = (float*)d_ws;              // NN*F
    float* h2     = node_h + NN * F;           // NN*F
    float* h2W    = h2 + NN * F;               // NN*F
    int* csr_e    = (int*)(h2W + NN * F);      // E
    int* csr_src  = csr_e + E;                 // E
    int* rowptr   = csr_src + E;               // NN+1
    int* cnt      = rowptr + NN + 1;           // NN
    int* cursor   = cnt + NN;                  // NN

    const int totN4 = NN * F4;                 // 600K
    const int totE4 = E * F4;                  // 19.2M

    k_zero<<<(NN + 255) / 256, 256, 0, stream>>>(cnt, NN);
    k_count<<<(E + 255) / 256, 256, 0, stream>>>(dst, cnt, E);
    k_scan<<<1, 1024, 0, stream>>>(cnt, rowptr, cursor, NN);
    k_fill<<<(E + 255) / 256, 256, 0, stream>>>(src, dst, cursor, csr_e, csr_src, E);
    k_node_h<<<(totN4 + 255) / 256, 256, 0, stream>>>(
        (const f32x4*)ef, csr_e, rowptr, (f32x4*)node_h, totN4);
    k_h2<<<(totN4 + 255) / 256, 256, 0, stream>>>(
        (const f32x4*)node_h, csr_src, rowptr, (f32x4*)h2, totN4);
    k_node_linear<<<(NN + 255) / 256, 256, 0, stream>>>(h2, W, b, h2W, NN);
    k_edge_out<<<(totE4 + 255) / 256, 256, 0, stream>>>(
        src, dst, (const f32x4*)h2W, (f32x4*)out, totE4);
}

// Round 6
// 487.285 us; speedup vs baseline: 4.5441x; 1.2090x over previous
//
#include <hip/hip_runtime.h>

// GCN layer, E=1.6M, N=50000, F=48.
//   node_h = segment_mean(edge_feats, dst)
//   h2     = segment_sum(node_h[src], dst)
//   out[e] = 0.5*(h2[src]+h2[dst]) @ W^T + b
// Algebra: h2W = 0.5*(h2 @ W^T) + 0.5*b (node level); out[e]=h2W[src]+h2W[dst].
// R2: fp atomics -> ~1 mem transaction per ~4 atomics; use CSR + gather.
// R3: in-graph hipMemsetAsync dispatches a slow fill -> own zero kernel.
// R4: __builtin_nontemporal_* needs native vector types, not HIP float4.
// R5: single-block strided scan was uncoalesced; csr as 2 arrays = 2x scatter
//     transactions. -> wave-shuffle tiled scan + int2 csr payload.

constexpr int NN = 50000;
constexpr int F  = 48;
constexpr int F4 = F / 4;

typedef float f32x4 __attribute__((ext_vector_type(4)));

// ---- tiny zero ----------------------------------------------------------
__global__ void k_zero(int* __restrict__ p, int n) {
    int i = blockIdx.x * blockDim.x + threadIdx.x;
    if (i < n) p[i] = 0;
}

// ---- CSR build ----------------------------------------------------------
__global__ void k_count(const int* __restrict__ dst, int* __restrict__ cnt, int E) {
    int e = blockIdx.x * blockDim.x + threadIdx.x;
    if (e < E) atomicAdd(&cnt[dst[e]], 1);
}

// single-block tiled scan: int4 coalesced IO, wave shfl scan, LDS wave fixup.
// n = 50000 (n4 = 12500 int4 exactly). Writes rowptr, cursor, rowptr[n].
__global__ __launch_bounds__(1024) void k_scan(
    const int4* __restrict__ cnt4, int4* __restrict__ rowptr4,
    int4* __restrict__ cursor4, int* __restrict__ rowptr, int n4, int n)
{
    __shared__ int wsum[16];
    __shared__ int carry_s;
    int t = threadIdx.x;
    int lane = t & 63, wid = t >> 6;
    if (t == 0) carry_s = 0;
    __syncthreads();
    for (int base = 0; base < n4; base += 1024) {
        int c0 = carry_s;
        int i4 = base + t;
        int4 v = (i4 < n4) ? cnt4[i4] : make_int4(0, 0, 0, 0);
        int tsum = v.x + v.y + v.z + v.w;
        int incl = tsum;
#pragma unroll
        for (int d = 1; d < 64; d <<= 1) {
            int u = __shfl_up(incl, d, 64);
            if (lane >= d) incl += u;
        }
        if (lane == 63) wsum[wid] = incl;
        __syncthreads();
        if (wid == 0) {
            int w = (lane < 16) ? wsum[lane] : 0;
            int wincl = w;
#pragma unroll
            for (int d = 1; d < 16; d <<= 1) {
                int u = __shfl_up(wincl, d, 64);
                if (lane >= d) wincl += u;
            }
            if (lane < 16) wsum[lane] = wincl - w;   // exclusive wave offset
        }
        __syncthreads();
        int excl = c0 + wsum[wid] + (incl - tsum);
        if (i4 < n4) {
            int p0 = excl, p1 = p0 + v.x, p2 = p1 + v.y, p3 = p2 + v.z;
            int4 r = make_int4(p0, p1, p2, p3);
            rowptr4[i4] = r;
            cursor4[i4] = r;
        }
        __syncthreads();
        if (t == 1023) carry_s = excl + tsum;   // c0 + tile total
        __syncthreads();
    }
    if (t == 0) rowptr[n] = carry_s;
}

// place {edge id, src} into dst-sorted order; one 8B scatter store per edge
__global__ void k_fill(const int* __restrict__ src, const int* __restrict__ dst,
                       int* __restrict__ cursor, int2* __restrict__ csr_es, int E) {
    int e = blockIdx.x * blockDim.x + threadIdx.x;
    if (e >= E) return;
    int pos = atomicAdd(&cursor[dst[e]], 1);
    csr_es[pos] = make_int2(e, src[e]);
}

// ---- gather-sums (thread per (node, float4)) ----------------------------
__global__ __launch_bounds__(256) void k_node_h(
    const f32x4* __restrict__ ef4, const int2* __restrict__ csr_es,
    const int* __restrict__ rowptr, f32x4* __restrict__ node_h4, int total)
{
    int idx = blockIdx.x * blockDim.x + threadIdx.x;
    if (idx >= total) return;
    int n = idx / F4;
    int q = idx - n * F4;
    int lo = rowptr[n], hi = rowptr[n + 1];
    f32x4 acc = (f32x4)(0.f);
    int j = lo;
    for (; j + 4 <= hi; j += 4) {           // 4 x 16B loads in flight
        int e0 = csr_es[j].x, e1 = csr_es[j + 1].x;
        int e2 = csr_es[j + 2].x, e3 = csr_es[j + 3].x;
        f32x4 a0 = __builtin_nontemporal_load(&ef4[e0 * F4 + q]);
        f32x4 a1 = __builtin_nontemporal_load(&ef4[e1 * F4 + q]);
        f32x4 a2 = __builtin_nontemporal_load(&ef4[e2 * F4 + q]);
        f32x4 a3 = __builtin_nontemporal_load(&ef4[e3 * F4 + q]);
        acc += a0 + a1 + a2 + a3;
    }
    for (; j < hi; j++)
        acc += __builtin_nontemporal_load(&ef4[csr_es[j].x * F4 + q]);
    float inv = 1.0f / fmaxf((float)(hi - lo), 1.0f);
    node_h4[idx] = acc * inv;
}

__global__ __launch_bounds__(256) void k_h2(
    const f32x4* __restrict__ nh4, const int2* __restrict__ csr_es,
    const int* __restrict__ rowptr, f32x4* __restrict__ h2_4, int total)
{
    int idx = blockIdx.x * blockDim.x + threadIdx.x;
    if (idx >= total) return;
    int n = idx / F4;
    int q = idx - n * F4;
    int lo = rowptr[n], hi = rowptr[n + 1];
    f32x4 acc = (f32x4)(0.f);
    int j = lo;
    for (; j + 4 <= hi; j += 4) {
        int s0 = csr_es[j].y, s1 = csr_es[j + 1].y;
        int s2 = csr_es[j + 2].y, s3 = csr_es[j + 3].y;
        f32x4 a0 = nh4[s0 * F4 + q];
        f32x4 a1 = nh4[s1 * F4 + q];
        f32x4 a2 = nh4[s2 * F4 + q];
        f32x4 a3 = nh4[s3 * F4 + q];
        acc += a0 + a1 + a2 + a3;
    }
    for (; j < hi; j++)
        acc += nh4[csr_es[j].y * F4 + q];
    h2_4[idx] = acc;
}

// ---- node-level linear --------------------------------------------------
__global__ __launch_bounds__(256) void k_node_linear(
    const float* __restrict__ h2, const float* __restrict__ W,
    const float* __restrict__ b, float* __restrict__ h2W, int n)
{
    int v = blockIdx.x * blockDim.x + threadIdx.x;
    if (v >= n) return;
    float eh[F];
    const float4* hr = (const float4*)(h2 + (long long)v * F);
#pragma unroll
    for (int i = 0; i < F4; i++) {
        float4 a = hr[i];
        eh[4 * i + 0] = a.x; eh[4 * i + 1] = a.y;
        eh[4 * i + 2] = a.z; eh[4 * i + 3] = a.w;
    }
    float4* o4 = (float4*)(h2W + (long long)v * F);
    for (int o = 0; o < F; o += 4) {
        float4 acc = make_float4(0.f, 0.f, 0.f, 0.f);
#pragma unroll
        for (int i = 0; i < F; i++) {
            acc.x += eh[i] * W[(o + 0) * F + i];
            acc.y += eh[i] * W[(o + 1) * F + i];
            acc.z += eh[i] * W[(o + 2) * F + i];
            acc.w += eh[i] * W[(o + 3) * F + i];
        }
        acc.x = 0.5f * acc.x + 0.5f * b[o + 0];
        acc.y = 0.5f * acc.y + 0.5f * b[o + 1];
        acc.z = 0.5f * acc.z + 0.5f * b[o + 2];
        acc.w = 0.5f * acc.w + 0.5f * b[o + 3];
        o4[o / 4] = acc;
    }
}

// thread per (edge, float4): out = h2W[src] + h2W[dst]
// wave stores are contiguous 1KB; nt store (write-once, keep h2W in L2)
__global__ void k_edge_out(const int* __restrict__ src, const int* __restrict__ dst,
                           const f32x4* __restrict__ h2W4, f32x4* __restrict__ out4, int total) {
    int idx = blockIdx.x * blockDim.x + threadIdx.x;
    if (idx >= total) return;
    int e = idx / F4;
    int q = idx - e * F4;
    f32x4 x = h2W4[src[e] * F4 + q];
    f32x4 y = h2W4[dst[e] * F4 + q];
    f32x4 r = x + y;
    __builtin_nontemporal_store(r, &out4[idx]);
}

extern "C" void kernel_launch(void* const* d_in, const int* in_sizes, int n_in,
                              void* d_out, int out_size, void* d_ws, size_t ws_size,
                              hipStream_t stream) {
    const float* ef  = (const float*)d_in[0];
    const int*   src = (const int*)d_in[1];
    const int*   dst = (const int*)d_in[2];
    const float* W   = (const float*)d_in[3];
    const float* b   = (const float*)d_in[4];
    float* out = (float*)d_out;
    const int E = in_sizes[1];

    // ws layout, all 16B aligned (sizes padded):
    float* node_h = (float*)d_ws;                  // NN*F        (9.6MB)
    float* h2     = node_h + NN * F;               // NN*F
    float* h2W    = h2 + NN * F;                   // NN*F
    int2* csr_es  = (int2*)(h2W + NN * F);         // E int2      (12.8MB)
    int* rowptr   = (int*)(csr_es + E);            // NN+1, padded to 50016
    int* cursor   = rowptr + 50016;                // NN, padded to 50016
    int* cnt      = cursor + 50016;                // NN, padded to 50016

    const int totN4 = NN * F4;                     // 600K
    const int totE4 = E * F4;                      // 19.2M
    const int n4 = NN / 4;                         // 12500 exact

    k_zero<<<(NN + 255) / 256, 256, 0, stream>>>(cnt, NN);
    k_count<<<(E + 255) / 256, 256, 0, stream>>>(dst, cnt, E);
    k_scan<<<1, 1024, 0, stream>>>((const int4*)cnt, (int4*)rowptr, (int4*)cursor,
                                   rowptr, n4, NN);
    k_fill<<<(E + 255) / 256, 256, 0, stream>>>(src, dst, cursor, csr_es, E);
    k_node_h<<<(totN4 + 255) / 256, 256, 0, stream>>>(
        (const f32x4*)ef, csr_es, rowptr, (f32x4*)node_h, totN4);
    k_h2<<<(totN4 + 255) / 256, 256, 0, stream>>>(
        (const f32x4*)node_h, csr_es, rowptr, (f32x4*)h2, totN4);
    k_node_linear<<<(NN + 255) / 256, 256, 0, stream>>>(h2, W, b, h2W, NN);
    k_edge_out<<<(totE4 + 255) / 256, 256, 0, stream>>>(
        src, dst, (const f32x4*)h2W, (f32x4*)out, totE4);
}

// Round 7
// 464.044 us; speedup vs baseline: 4.7717x; 1.0501x over previous
//
#include <hip/hip_runtime.h>

// GCN layer, E=1.6M, N=50000, F=48.
//   node_h = segment_mean(edge_feats, dst)
//   h2     = segment_sum(node_h[src], dst)
//   out[e] = 0.5*(h2[src]+h2[dst]) @ W^T + b
// Algebra: h2W = 0.5*(h2 @ W^T) + 0.5*b (node level); out[e]=h2W[src]+h2W[dst].
// R2: fp atomics -> ~1 mem transaction per ~4 atomics; use CSR + gather.
// R3: in-graph hipMemsetAsync dispatches a slow fill -> own zero kernel.
// R4: __builtin_nontemporal_* needs native vector types, not HIP float4.
// R5: coalesce the scan; int2 csr payload (one scatter store per edge).
// R7: f16 node tables (halve gather bytes, h2W fits XCD L2); fuse h2+linear.

constexpr int NN = 50000;
constexpr int F  = 48;
constexpr int F4 = F / 4;

typedef float    f32x4 __attribute__((ext_vector_type(4)));
typedef _Float16 f16x4 __attribute__((ext_vector_type(4)));

// ---- tiny zero ----------------------------------------------------------
__global__ void k_zero(int* __restrict__ p, int n) {
    int i = blockIdx.x * blockDim.x + threadIdx.x;
    if (i < n) p[i] = 0;
}

// ---- CSR build ----------------------------------------------------------
// 4 edges per thread, int4 coalesced dst reads
__global__ void k_count(const int4* __restrict__ dst4, int* __restrict__ cnt, int E4) {
    int i = blockIdx.x * blockDim.x + threadIdx.x;
    if (i >= E4) return;
    int4 d = dst4[i];
    atomicAdd(&cnt[d.x], 1);
    atomicAdd(&cnt[d.y], 1);
    atomicAdd(&cnt[d.z], 1);
    atomicAdd(&cnt[d.w], 1);
}

// single-block tiled scan: int4 coalesced IO, wave shfl scan, LDS wave fixup.
__global__ __launch_bounds__(1024) void k_scan(
    const int4* __restrict__ cnt4, int4* __restrict__ rowptr4,
    int4* __restrict__ cursor4, int* __restrict__ rowptr, int n4, int n)
{
    __shared__ int wsum[16];
    __shared__ int carry_s;
    int t = threadIdx.x;
    int lane = t & 63, wid = t >> 6;
    if (t == 0) carry_s = 0;
    __syncthreads();
    for (int base = 0; base < n4; base += 1024) {
        int c0 = carry_s;
        int i4 = base + t;
        int4 v = (i4 < n4) ? cnt4[i4] : make_int4(0, 0, 0, 0);
        int tsum = v.x + v.y + v.z + v.w;
        int incl = tsum;
#pragma unroll
        for (int d = 1; d < 64; d <<= 1) {
            int u = __shfl_up(incl, d, 64);
            if (lane >= d) incl += u;
        }
        if (lane == 63) wsum[wid] = incl;
        __syncthreads();
        if (wid == 0) {
            int w = (lane < 16) ? wsum[lane] : 0;
            int wincl = w;
#pragma unroll
            for (int d = 1; d < 16; d <<= 1) {
                int u = __shfl_up(wincl, d, 64);
                if (lane >= d) wincl += u;
            }
            if (lane < 16) wsum[lane] = wincl - w;   // exclusive wave offset
        }
        __syncthreads();
        int excl = c0 + wsum[wid] + (incl - tsum);
        if (i4 < n4) {
            int p0 = excl, p1 = p0 + v.x, p2 = p1 + v.y, p3 = p2 + v.z;
            int4 r = make_int4(p0, p1, p2, p3);
            rowptr4[i4] = r;
            cursor4[i4] = r;
        }
        __syncthreads();
        if (t == 1023) carry_s = excl + tsum;
        __syncthreads();
    }
    if (t == 0) rowptr[n] = carry_s;
}

// place {edge id, src} into dst-sorted order; 4 edges/thread
__global__ void k_fill(const int4* __restrict__ src4, const int4* __restrict__ dst4,
                       int* __restrict__ cursor, int2* __restrict__ csr_es, int E4) {
    int i = blockIdx.x * blockDim.x + threadIdx.x;
    if (i >= E4) return;
    int4 s = src4[i];
    int4 d = dst4[i];
    int e = i * 4;
    int p0 = atomicAdd(&cursor[d.x], 1);
    int p1 = atomicAdd(&cursor[d.y], 1);
    int p2 = atomicAdd(&cursor[d.z], 1);
    int p3 = atomicAdd(&cursor[d.w], 1);
    csr_es[p0] = make_int2(e + 0, s.x);
    csr_es[p1] = make_int2(e + 1, s.y);
    csr_es[p2] = make_int2(e + 2, s.z);
    csr_es[p3] = make_int2(e + 3, s.w);
}

// ---- node_h: thread per (node, f32x4 quad); writes f16 rows --------------
__global__ __launch_bounds__(256) void k_node_h(
    const f32x4* __restrict__ ef4, const int2* __restrict__ csr_es,
    const int* __restrict__ rowptr, f16x4* __restrict__ nh16, int total)
{
    int idx = blockIdx.x * blockDim.x + threadIdx.x;
    if (idx >= total) return;
    int n = idx / F4;
    int q = idx - n * F4;
    int lo = rowptr[n], hi = rowptr[n + 1];
    f32x4 acc = (f32x4)(0.f);
    int j = lo;
    for (; j + 8 <= hi; j += 8) {           // 8 x 16B loads in flight
        int e0 = csr_es[j].x,     e1 = csr_es[j + 1].x;
        int e2 = csr_es[j + 2].x, e3 = csr_es[j + 3].x;
        int e4 = csr_es[j + 4].x, e5 = csr_es[j + 5].x;
        int e6 = csr_es[j + 6].x, e7 = csr_es[j + 7].x;
        f32x4 a0 = __builtin_nontemporal_load(&ef4[e0 * F4 + q]);
        f32x4 a1 = __builtin_nontemporal_load(&ef4[e1 * F4 + q]);
        f32x4 a2 = __builtin_nontemporal_load(&ef4[e2 * F4 + q]);
        f32x4 a3 = __builtin_nontemporal_load(&ef4[e3 * F4 + q]);
        f32x4 a4 = __builtin_nontemporal_load(&ef4[e4 * F4 + q]);
        f32x4 a5 = __builtin_nontemporal_load(&ef4[e5 * F4 + q]);
        f32x4 a6 = __builtin_nontemporal_load(&ef4[e6 * F4 + q]);
        f32x4 a7 = __builtin_nontemporal_load(&ef4[e7 * F4 + q]);
        acc += a0 + a1 + a2 + a3 + a4 + a5 + a6 + a7;
    }
    for (; j < hi; j++)
        acc += __builtin_nontemporal_load(&ef4[csr_es[j].x * F4 + q]);
    float inv = 1.0f / fmaxf((float)(hi - lo), 1.0f);
    acc *= inv;
    nh16[idx] = __builtin_convertvector(acc, f16x4);
}

// ---- fused h2-aggregate + linear: block = 192 threads = 16 nodes x 12 ----
__global__ __launch_bounds__(192) void k_h2lin(
    const f16x4* __restrict__ nh16, const int2* __restrict__ csr_es,
    const int* __restrict__ rowptr, const float* __restrict__ W,
    const float* __restrict__ b, f16x4* __restrict__ h2W16)
{
    __shared__ float h2s[16][F + 1];        // +1 pad: kill 3-way bank conflict
    int t = threadIdx.x;
    int nl = t / F4, q = t - nl * F4;       // node-local 0..15, quad 0..11
    int node = blockIdx.x * 16 + nl;        // NN = 3125*16 exactly

    int lo = rowptr[node], hi = rowptr[node + 1];
    f32x4 acc = (f32x4)(0.f);
    int j = lo;
    for (; j + 4 <= hi; j += 4) {
        int s0 = csr_es[j].y,     s1 = csr_es[j + 1].y;
        int s2 = csr_es[j + 2].y, s3 = csr_es[j + 3].y;
        f32x4 a0 = __builtin_convertvector(nh16[s0 * F4 + q], f32x4);
        f32x4 a1 = __builtin_convertvector(nh16[s1 * F4 + q], f32x4);
        f32x4 a2 = __builtin_convertvector(nh16[s2 * F4 + q], f32x4);
        f32x4 a3 = __builtin_convertvector(nh16[s3 * F4 + q], f32x4);
        acc += a0 + a1 + a2 + a3;
    }
    for (; j < hi; j++)
        acc += __builtin_convertvector(nh16[csr_es[j].y * F4 + q], f32x4);

    h2s[nl][q * 4 + 0] = acc.x;
    h2s[nl][q * 4 + 1] = acc.y;
    h2s[nl][q * 4 + 2] = acc.z;
    h2s[nl][q * 4 + 3] = acc.w;
    __syncthreads();

    // this thread computes output features o = q*4 .. q*4+3 of its node
    const float* row = h2s[nl];
    const float* W0 = W + (q * 4 + 0) * F;
    const float* W1 = W + (q * 4 + 1) * F;
    const float* W2 = W + (q * 4 + 2) * F;
    const float* W3 = W + (q * 4 + 3) * F;
    float o0 = 0.f, o1 = 0.f, o2 = 0.f, o3 = 0.f;
#pragma unroll
    for (int i = 0; i < F; i++) {
        float hv = row[i];
        o0 += hv * W0[i];
        o1 += hv * W1[i];
        o2 += hv * W2[i];
        o3 += hv * W3[i];
    }
    const f32x4* b4 = (const f32x4*)b;
    f32x4 r; r.x = o0; r.y = o1; r.z = o2; r.w = o3;
    r = 0.5f * r + 0.5f * b4[q];
    h2W16[node * F4 + q] = __builtin_convertvector(r, f16x4);
}

// ---- edge out: thread per (edge, quad); f16 gathers, f32 nt store --------
__global__ void k_edge_out(const int* __restrict__ src, const int* __restrict__ dst,
                           const f16x4* __restrict__ h2W16, f32x4* __restrict__ out4,
                           int total) {
    int idx = blockIdx.x * blockDim.x + threadIdx.x;
    if (idx >= total) return;
    int e = idx / F4;
    int q = idx - e * F4;
    f32x4 x = __builtin_convertvector(h2W16[src[e] * F4 + q], f32x4);
    f32x4 y = __builtin_convertvector(h2W16[dst[e] * F4 + q], f32x4);
    f32x4 r = x + y;
    __builtin_nontemporal_store(r, &out4[idx]);
}

extern "C" void kernel_launch(void* const* d_in, const int* in_sizes, int n_in,
                              void* d_out, int out_size, void* d_ws, size_t ws_size,
                              hipStream_t stream) {
    const float* ef  = (const float*)d_in[0];
    const int*   src = (const int*)d_in[1];
    const int*   dst = (const int*)d_in[2];
    const float* W   = (const float*)d_in[3];
    const float* b   = (const float*)d_in[4];
    float* out = (float*)d_out;
    const int E = in_sizes[1];

    // ws layout, 16B-aligned sections:
    _Float16* nh16  = (_Float16*)d_ws;             // NN*F halves (4.8MB)
    _Float16* h2W16 = nh16 + NN * F;               // NN*F halves (4.8MB)
    int2* csr_es    = (int2*)(h2W16 + NN * F);     // E int2 (12.8MB)
    int* rowptr     = (int*)(csr_es + E);          // NN+1, padded to 50016
    int* cursor     = rowptr + 50016;
    int* cnt        = cursor + 50016;

    const int totN4 = NN * F4;                     // 600K
    const int totE4 = E * F4;                      // 19.2M
    const int n4 = NN / 4;                         // 12500 exact
    const int E4 = (E + 3) / 4;                    // 400K (E divisible by 4)

    k_zero<<<(NN + 255) / 256, 256, 0, stream>>>(cnt, NN);
    k_count<<<(E4 + 255) / 256, 256, 0, stream>>>((const int4*)dst, cnt, E4);
    k_scan<<<1, 1024, 0, stream>>>((const int4*)cnt, (int4*)rowptr, (int4*)cursor,
                                   rowptr, n4, NN);
    k_fill<<<(E4 + 255) / 256, 256, 0, stream>>>(
        (const int4*)src, (const int4*)dst, cursor, csr_es, E4);
    k_node_h<<<(totN4 + 255) / 256, 256, 0, stream>>>(
        (const f32x4*)ef, csr_es, rowptr, (f16x4*)nh16, totN4);
    k_h2lin<<<NN / 16, 192, 0, stream>>>(
        (const f16x4*)nh16, csr_es, rowptr, W, b, (f16x4*)h2W16);
    k_edge_out<<<(totE4 + 255) / 256, 256, 0, stream>>>(
        src, dst, (const f16x4*)h2W16, (f32x4*)out, totE4);
}